// Round 18
// baseline (452.938 us; speedup 1.0000x reference)
//
#include <hip/hip_runtime.h>

#define BN_EPS 1e-5f

typedef float f32x4 __attribute__((ext_vector_type(4)));
typedef short s16x8 __attribute__((ext_vector_type(8)));

__device__ __forceinline__ short f2bf(float f) {
    unsigned u = __builtin_bit_cast(unsigned, f);
    u = (u + 0x7fffu + ((u >> 16) & 1u)) >> 16;   // RNE
    return (short)u;
}

// ============ fused fp32 -> bf16 convert of all 9 tensors (8 elems/thread) ============
__global__ __launch_bounds__(256) void cvt_multi_kernel(
    const float* __restrict__ s0, const float* __restrict__ s1, const float* __restrict__ s2,
    const float* __restrict__ s3, const float* __restrict__ s4, const float* __restrict__ s5,
    const float* __restrict__ s6, const float* __restrict__ s7, const float* __restrict__ s8,
    short* __restrict__ d0, short* __restrict__ d1, short* __restrict__ d2,
    short* __restrict__ d3, short* __restrict__ d4, short* __restrict__ d5,
    short* __restrict__ d6, short* __restrict__ d7, short* __restrict__ d8)
{
    int idx = blockIdx.x * 256 + threadIdx.x;   // chunk of 8 floats
    const float* src; short* dst; int local;
    if      (idx <   50176) { src = s0; dst = d0; local = idx; }
    else if (idx <  443392) { src = s1; dst = d1; local = idx -   50176; }
    else if (idx <  476160) { src = s2; dst = d2; local = idx -  443392; }
    else if (idx <  508928) { src = s3; dst = d3; local = idx -  476160; }
    else if (idx <  574464) { src = s4; dst = d4; local = idx -  508928; }
    else if (idx <  607232) { src = s5; dst = d5; local = idx -  574464; }
    else if (idx <  934912) { src = s6; dst = d6; local = idx -  607232; }
    else if (idx < 1065984) { src = s7; dst = d7; local = idx -  934912; }
    else if (idx < 1098752) { src = s8; dst = d8; local = idx - 1065984; }
    else return;
    const float4* s4p = reinterpret_cast<const float4*>(src) + (size_t)local * 2;
    float4 a = s4p[0], b = s4p[1];
    s16x8 v;
    v[0] = f2bf(a.x); v[1] = f2bf(a.y); v[2] = f2bf(a.z); v[3] = f2bf(a.w);
    v[4] = f2bf(b.x); v[5] = f2bf(b.y); v[6] = f2bf(b.z); v[7] = f2bf(b.w);
    reinterpret_cast<s16x8*>(dst)[local] = v;
}

// ============ MFMA bf16 linear: Y = act(X @ W^T + b), bf16 in ============
// 64x64 tile, BK=32, 4 waves each computing a 32x32 quadrant (2x2 of 16x16x32 MFMA).
// OMODE 0: fp32 out. 1: bf16 out. 2: bf16 out transposed per-49-row tile
// -> [tile][Cout=512][64] (keys padded to 64; pad pre-zeroed by host memset).
template<int OMODE>
__global__ __launch_bounds__(256) void mfma_linear_kernel(
    const short* __restrict__ X, int Xstride,
    const short* __restrict__ W, int Wstride,
    const float* __restrict__ bias, int bstride,
    void* __restrict__ Yv, int Ystride,
    int R, int Cin, int Cout, int relu)
{
    const int mat = blockIdx.z;
    X += (size_t)mat * Xstride;
    W += (size_t)mat * Wstride;
    const float* bp = bias ? bias + mat * bstride : nullptr;
    float* Yf = (float*)Yv + (size_t)mat * Ystride;
    short* Ys = (short*)Yv + (size_t)mat * Ystride;

    const int r0 = blockIdx.y * 64;
    const int o0 = blockIdx.x * 64;

    __shared__ short As[64 * 40];
    __shared__ short Bs[64 * 40];

    const int tid = threadIdx.x;
    const int lane = tid & 63;
    const int wave = tid >> 6;
    const int wr = wave >> 1, wc = wave & 1;
    const int l15 = lane & 15;
    const int lk = lane >> 4;

    const int trow = tid >> 2;
    const int tseg = (tid & 3) * 8;

    f32x4 acc[2][2] = {};

    const int arow = r0 + trow;
    const bool aok = arow < R;
    const short* xrow = X + (size_t)arow * Cin + tseg;
    const short* wrow = W + (size_t)(o0 + trow) * Cin + tseg;

    for (int k0 = 0; k0 < Cin; k0 += 32) {
        s16x8 av = {};
        if (aok) av = *reinterpret_cast<const s16x8*>(xrow + k0);
        s16x8 bv = *reinterpret_cast<const s16x8*>(wrow + k0);
        *reinterpret_cast<s16x8*>(&As[trow * 40 + tseg]) = av;
        *reinterpret_cast<s16x8*>(&Bs[trow * 40 + tseg]) = bv;
        __syncthreads();

        s16x8 af[2], bf[2];
        #pragma unroll
        for (int mi = 0; mi < 2; mi++)
            af[mi] = *reinterpret_cast<const s16x8*>(&As[(wr * 32 + mi * 16 + l15) * 40 + lk * 8]);
        #pragma unroll
        for (int ni = 0; ni < 2; ni++)
            bf[ni] = *reinterpret_cast<const s16x8*>(&Bs[(wc * 32 + ni * 16 + l15) * 40 + lk * 8]);
        #pragma unroll
        for (int mi = 0; mi < 2; mi++)
            #pragma unroll
            for (int ni = 0; ni < 2; ni++)
                acc[mi][ni] = __builtin_amdgcn_mfma_f32_16x16x32_bf16(af[mi], bf[ni], acc[mi][ni], 0, 0, 0);
        __syncthreads();
    }

    #pragma unroll
    for (int mi = 0; mi < 2; mi++) {
        #pragma unroll
        for (int ni = 0; ni < 2; ni++) {
            int col = o0 + wc * 32 + ni * 16 + l15;
            int row0 = r0 + wr * 32 + mi * 16 + lk * 4;
            float bb = bp ? bp[col] : 0.f;
            #pragma unroll
            for (int r = 0; r < 4; r++) {
                int row = row0 + r;
                if (row < R) {
                    float v = acc[mi][ni][r] + bb;
                    if (relu) v = fmaxf(v, 0.f);
                    if (OMODE == 0) {
                        Yf[(size_t)row * Cout + col] = v;
                    } else if (OMODE == 1) {
                        Ys[(size_t)row * Cout + col] = f2bf(v);
                    } else {
                        int t = row / 49, n = row - t * 49;
                        Ys[((size_t)t * 512 + col) * 64 + n] = f2bf(v);
                    }
                }
            }
        }
    }
}

// ============ BN1 partial stats: grid (12, 8); atomicAdd (sum, sumsq) per (k,o) ============
__global__ __launch_bounds__(256) void bn1_partial_kernel(
    const float* __restrict__ h, float* __restrict__ bsum, float* __restrict__ bsq)
{
    int k = blockIdx.x;
    int part = blockIdx.y;
    int tid = threadIdx.x;
    #pragma unroll
    for (int half = 0; half < 2; half++) {
        int o = tid + half * 256;
        const float* base = h + (size_t)k * 401408 + (size_t)part * 98 * 512 + o;
        float s = 0.f, sq = 0.f;
        #pragma unroll 7
        for (int bn = 0; bn < 98; bn++) {
            float v = base[bn * 512];
            s += v; sq += v * v;
        }
        atomicAdd(&bsum[k * 512 + o], s);
        atomicAdd(&bsq[k * 512 + o], sq);
    }
}

// ============ f_u = relu(bn(h)) -> bf16; f_v = mean_n (fp32 + bf16) ============
__global__ __launch_bounds__(256) void fu_fv_kernel(
    const float* __restrict__ h, const float* __restrict__ bsum,
    const float* __restrict__ bsq, short* __restrict__ fu_bf,
    float* __restrict__ f_v, short* __restrict__ fv_bf)
{
    int b = blockIdx.x;
    int k = blockIdx.y;
    int tid = threadIdx.x;
    #pragma unroll
    for (int half = 0; half < 2; half++) {
        int o = tid + half * 256;
        float mu = bsum[k * 512 + o] * (1.f / 784.f);
        float var = bsq[k * 512 + o] * (1.f / 784.f) - mu * mu;
        float rs = rsqrtf(var + BN_EPS);
        const float* base = h + (size_t)(k * 16 + b) * 49 * 512 + o;
        short* obase = fu_bf + (size_t)(k * 16 + b) * 49 * 512 + o;
        float acc = 0.f;
        #pragma unroll 7
        for (int n = 0; n < 49; n++) {
            float v = (base[n * 512] - mu) * rs;
            v = fmaxf(v, 0.f);
            obase[n * 512] = f2bf(v);
            acc += v;
        }
        float fvv = acc * (1.f / 49.f);
        f_v[(b * 12 + k) * 512 + o] = fvv;
        fv_bf[(b * 12 + k) * 512 + o] = f2bf(fvv);
    }
}

// ============ attn1 MFMA: block per (b,k); bf16 q1/k1, v1T transposed; writes feat bf16 ============
__global__ __launch_bounds__(256) void attn1_mfma_kernel(
    const short* __restrict__ q1,   // (12,16,49,256) bf16
    const short* __restrict__ k1,   // (16,49,256) bf16
    const short* __restrict__ v1T,  // (16,512,64) bf16, pad keys zeroed
    short* __restrict__ feat)       // (12,16,49,512) bf16
{
    const int b = blockIdx.x, k = blockIdx.y;
    __shared__ float S[64 * 68];
    __shared__ short P[64 * 88];
    const int tid = threadIdx.x;
    const int lane = tid & 63, w = tid >> 6;
    const int l15 = lane & 15, lk = lane >> 4;

    for (int idx = tid; idx < 64 * 88; idx += 256) P[idx] = 0;
    const short* qb = q1 + (size_t)((k * 16 + b) * 49) * 256;
    const short* kb = k1 + (size_t)(b * 49) * 256;
    __syncthreads();

    {
        int qrow = w * 16 + l15; if (qrow > 48) qrow = 48;
        f32x4 sacc[4] = {};
        #pragma unroll
        for (int ks = 0; ks < 8; ks++) {
            s16x8 aq = *reinterpret_cast<const s16x8*>(qb + (size_t)qrow * 256 + ks * 32 + lk * 8);
            #pragma unroll
            for (int ni = 0; ni < 4; ni++) {
                int krow = ni * 16 + l15; if (krow > 48) krow = 48;
                s16x8 bk = *reinterpret_cast<const s16x8*>(kb + (size_t)krow * 256 + ks * 32 + lk * 8);
                sacc[ni] = __builtin_amdgcn_mfma_f32_16x16x32_bf16(aq, bk, sacc[ni], 0, 0, 0);
            }
        }
        #pragma unroll
        for (int ni = 0; ni < 4; ni++)
            #pragma unroll
            for (int r = 0; r < 4; r++)
                S[(w * 16 + lk * 4 + r) * 68 + ni * 16 + l15] = sacc[ni][r] * 0.0625f;
    }
    __syncthreads();

    if (tid < 196) {
        int qi = tid >> 2, sub = tid & 3;
        float ev[13];
        float m = -1e30f;
        #pragma unroll 13
        for (int t = 0; t < 13; t++) {
            int kk = sub + t * 4;
            ev[t] = (kk < 49) ? S[qi * 68 + kk] : -1e30f;
            m = fmaxf(m, ev[t]);
        }
        m = fmaxf(m, __shfl_xor(m, 1));
        m = fmaxf(m, __shfl_xor(m, 2));
        float s = 0.f;
        #pragma unroll 13
        for (int t = 0; t < 13; t++) { ev[t] = __expf(ev[t] - m); s += ev[t]; }
        s += __shfl_xor(s, 1);
        s += __shfl_xor(s, 2);
        float inv = 1.f / s;
        #pragma unroll 13
        for (int t = 0; t < 13; t++) {
            int kk = sub + t * 4;
            if (kk < 49) P[qi * 88 + kk] = f2bf(ev[t] * inv);
        }
    }
    __syncthreads();

    const short* vt = v1T + (size_t)b * 512 * 64;
    short* fb = feat + (size_t)((k * 16 + b) * 49) * 512;
    #pragma unroll
    for (int half = 0; half < 2; half++) {
        const int cb = half * 256 + w * 64;
        f32x4 pac[4][4] = {};
        #pragma unroll
        for (int ks = 0; ks < 2; ks++) {
            s16x8 bv[4];
            #pragma unroll
            for (int ni = 0; ni < 4; ni++) {
                int ch = cb + ni * 16 + l15;
                bv[ni] = *reinterpret_cast<const s16x8*>(vt + (size_t)ch * 64 + ks * 32 + lk * 8);
            }
            #pragma unroll
            for (int mi = 0; mi < 4; mi++) {
                s16x8 ap = *reinterpret_cast<const s16x8*>(&P[(mi * 16 + l15) * 88 + ks * 32 + lk * 8]);
                #pragma unroll
                for (int ni = 0; ni < 4; ni++)
                    pac[mi][ni] = __builtin_amdgcn_mfma_f32_16x16x32_bf16(ap, bv[ni], pac[mi][ni], 0, 0, 0);
            }
        }
        #pragma unroll
        for (int ni = 0; ni < 4; ni++) {
            int col = cb + ni * 16 + l15;
            #pragma unroll
            for (int mi = 0; mi < 4; mi++) {
                #pragma unroll
                for (int r = 0; r < 4; r++) {
                    int row = mi * 16 + lk * 4 + r;
                    if (row < 49)
                        fb[(size_t)row * 512 + col] = f2bf(pac[mi][ni][r]);
                }
            }
        }
    }
}

// ============ attn2 MFMA v4b: 512 threads, 2 wave-groups, launch_bounds(512,2) (VGPR<=256, no spill) ============
__global__ __launch_bounds__(512, 2) void attn2_mfma_kernel(
    const short* __restrict__ q2,
    const short* __restrict__ k2,
    const short* __restrict__ w2vT,
    const float* __restrict__ ep_b,
    float* __restrict__ fe_raw,     // (16,144,512)
    float* __restrict__ stats)      // (144,2)
{
    const int b = blockIdx.x, i = blockIdx.y;
    __shared__ short Vs[512 * 64];      // 64 KB, swizzled
    __shared__ float S[2][64 * 68];     // 34.8 KB
    __shared__ short P[2][64 * 88];     // 22.5 KB
    const int tid = threadIdx.x;        // 0..511
    const int lane = tid & 63;
    const int wave = tid >> 6;          // 0..7
    const int g = wave >> 2;            // wave-group 0/1
    const int w = wave & 3;             // wave-in-group 0..3
    const int gtid = tid & 255;         // thread-in-group 0..255
    const int l15 = lane & 15, lk = lane >> 4;

    // ---- stage V tile (all 512 threads), zero both P buffers ----
    {
        const float4* src = reinterpret_cast<const float4*>(w2vT + (size_t)((i * 16 + b) * 512) * 64);
        float4* dst = reinterpret_cast<float4*>(Vs);
        #pragma unroll
        for (int it = 0; it < 8; it++) {
            int c = tid + it * 512;          // 16B chunk 0..4095
            int ch = c >> 3, c8 = c & 7;
            dst[(ch << 3) | (c8 ^ (ch & 7))] = src[c];
        }
        short* pz = &P[0][0];
        for (int idx = tid; idx < 2 * 64 * 88; idx += 512) pz[idx] = 0;
    }
    const short* kb = k2 + (size_t)((i * 16 + b) * 49) * 256;
    __syncthreads();

    for (int jj = 0; jj < 6; jj++) {
        const int j = g * 6 + jj;
        const short* qb = q2 + (size_t)((j * 16 + b) * 49) * 256;
        // ---- QK^T (per group, into S[g]) ----
        {
            int qrow = w * 16 + l15; if (qrow > 48) qrow = 48;
            f32x4 sacc[4] = {};
            #pragma unroll
            for (int ks = 0; ks < 8; ks++) {
                s16x8 aq = *reinterpret_cast<const s16x8*>(qb + (size_t)qrow * 256 + ks * 32 + lk * 8);
                #pragma unroll
                for (int ni = 0; ni < 4; ni++) {
                    int krow = ni * 16 + l15; if (krow > 48) krow = 48;
                    s16x8 bk = *reinterpret_cast<const s16x8*>(kb + (size_t)krow * 256 + ks * 32 + lk * 8);
                    sacc[ni] = __builtin_amdgcn_mfma_f32_16x16x32_bf16(aq, bk, sacc[ni], 0, 0, 0);
                }
            }
            #pragma unroll
            for (int ni = 0; ni < 4; ni++)
                #pragma unroll
                for (int r = 0; r < 4; r++)
                    S[g][(w * 16 + lk * 4 + r) * 68 + ni * 16 + l15] = sacc[ni][r] * 0.0625f;
        }
        __syncthreads();

        // ---- softmax rows 0..48 over keys 0..48 (group-local 196 threads) ----
        if (gtid < 196) {
            int qi = gtid >> 2, sub = gtid & 3;
            float ev[13];
            float m = -1e30f;
            #pragma unroll 13
            for (int t = 0; t < 13; t++) {
                int kk = sub + t * 4;
                ev[t] = (kk < 49) ? S[g][qi * 68 + kk] : -1e30f;
                m = fmaxf(m, ev[t]);
            }
            m = fmaxf(m, __shfl_xor(m, 1));
            m = fmaxf(m, __shfl_xor(m, 2));
            float s = 0.f;
            #pragma unroll 13
            for (int t = 0; t < 13; t++) { ev[t] = __expf(ev[t] - m); s += ev[t]; }
            s += __shfl_xor(s, 1);
            s += __shfl_xor(s, 2);
            float inv = 1.f / s;
            #pragma unroll 13
            for (int t = 0; t < 13; t++) {
                int kk = sub + t * 4;
                if (kk < 49) P[g][qi * 88 + kk] = f2bf(ev[t] * inv);
            }
        }
        __syncthreads();

        // ---- PV from LDS V (per group, P[g]) ----
        const int slot = i * 12 + j;
        float tot = 0.f, csq = 0.f;
        #pragma unroll
        for (int half = 0; half < 2; half++) {
            const int cb = half * 256 + w * 64;
            f32x4 pac[4][4] = {};
            #pragma unroll
            for (int ks = 0; ks < 2; ks++) {
                s16x8 bv[4];
                #pragma unroll
                for (int ni = 0; ni < 4; ni++) {
                    int ch = cb + ni * 16 + l15;
                    int boff = ((ch * 64 + ks * 32 + lk * 8) * 2) ^ ((ch & 7) << 4);
                    bv[ni] = *reinterpret_cast<const s16x8*>(reinterpret_cast<const char*>(Vs) + boff);
                }
                #pragma unroll
                for (int mi = 0; mi < 4; mi++) {
                    s16x8 ap = *reinterpret_cast<const s16x8*>(&P[g][(mi * 16 + l15) * 88 + ks * 32 + lk * 8]);
                    #pragma unroll
                    for (int ni = 0; ni < 4; ni++)
                        pac[mi][ni] = __builtin_amdgcn_mfma_f32_16x16x32_bf16(ap, bv[ni], pac[mi][ni], 0, 0, 0);
                }
            }
            #pragma unroll
            for (int ni = 0; ni < 4; ni++) {
                int col = cb + ni * 16 + l15;
                float bias = ep_b[col];
                float cs = 0.f;
                #pragma unroll
                for (int mi = 0; mi < 4; mi++) {
                    #pragma unroll
                    for (int r = 0; r < 4; r++) {
                        int row = mi * 16 + lk * 4 + r;
                        if (row < 49) {
                            float sv = pac[mi][ni][r] + bias;
                            cs += sv; csq += sv * sv;
                        }
                    }
                }
                tot += cs;
                cs += __shfl_xor(cs, 16);
                cs += __shfl_xor(cs, 32);
                if (lk == 0)
                    fe_raw[((size_t)b * 144 + slot) * 512 + col] = cs * (1.f / 49.f);
            }
        }
        tot += __shfl_xor(tot, 1);  tot += __shfl_xor(tot, 2);  tot += __shfl_xor(tot, 4);
        tot += __shfl_xor(tot, 8);  tot += __shfl_xor(tot, 16); tot += __shfl_xor(tot, 32);
        csq += __shfl_xor(csq, 1);  csq += __shfl_xor(csq, 2);  csq += __shfl_xor(csq, 4);
        csq += __shfl_xor(csq, 8);  csq += __shfl_xor(csq, 16); csq += __shfl_xor(csq, 32);
        if (lane == 0) {
            atomicAdd(&stats[slot * 2], tot);
            atomicAdd(&stats[slot * 2 + 1], csq);
        }
    }
}

// ============ finalize edge BN (fp32 + bf16 copy) ============
__global__ __launch_bounds__(256) void edge_fin_kernel(
    const float* __restrict__ stats, float* __restrict__ fe, short* __restrict__ fe_bf)
{
    int s = blockIdx.x;
    const float inv = 1.f / 401408.f;
    float mu = stats[s * 2] * inv;
    float var = stats[s * 2 + 1] * inv - mu * mu;
    float rs = rsqrtf(var + BN_EPS);
    int tid = threadIdx.x;
    for (int b = 0; b < 16; b++) {
        float* p = fe + (b * 144 + s) * 512;
        short* pb = fe_bf + (b * 144 + s) * 512;
        #pragma unroll
        for (int half = 0; half < 2; half++) {
            int c = tid + half * 256;
            float nv = (p[c] - mu) * rs;
            p[c] = nv;
            pb[c] = f2bf(nv);
        }
    }
}

// ============ GNN edge update (fp32 + bf16 copy) ============
__global__ __launch_bounds__(256) void gnn_edge_kernel(
    const float* __restrict__ nodeproj,
    const float* __restrict__ eE,
    float* __restrict__ fe, short* __restrict__ fe_bf)
{
    int s = blockIdx.x;
    int i = s / 12, j = s - i * 12;
    int tid = threadIdx.x;
    const float* Vix = nodeproj + 2 * 98304;
    const float* Vjx = nodeproj + 3 * 98304;
    __shared__ float red[256];
    float msg[32];
    float sum = 0.f, sq = 0.f;
    int idx = 0;
    for (int b = 0; b < 16; b++) {
        #pragma unroll
        for (int half = 0; half < 2; half++) {
            int c = tid + half * 256;
            float v = Vjx[(b * 12 + i) * 512 + c] + Vix[(b * 12 + j) * 512 + c]
                    + eE[(b * 144 + s) * 512 + c];
            msg[idx++] = v;
            sum += v; sq += v * v;
        }
    }
    red[tid] = sum; __syncthreads();
    for (int t = 128; t > 0; t >>= 1) { if (tid < t) red[tid] += red[tid + t]; __syncthreads(); }
    float tsum = red[0]; __syncthreads();
    red[tid] = sq; __syncthreads();
    for (int t = 128; t > 0; t >>= 1) { if (tid < t) red[tid] += red[tid + t]; __syncthreads(); }
    float tsq = red[0];
    float mu = tsum * (1.f / 8192.f);
    float var = tsq * (1.f / 8192.f) - mu * mu;
    float rs = rsqrtf(var + BN_EPS);
    idx = 0;
    for (int b = 0; b < 16; b++) {
        #pragma unroll
        for (int half = 0; half < 2; half++) {
            int c = tid + half * 256;
            int o = (b * 144 + s) * 512 + c;
            float v = fmaxf((msg[idx++] - mu) * rs, 0.f);
            float nv = fe[o] + v;
            fe[o] = nv;
            fe_bf[o] = f2bf(nv);
        }
    }
}

// ============ GNN aggregation: grid (16,12); atomicAdd into xn_agg ============
__global__ __launch_bounds__(256) void gnn_agg_kernel(
    const float* __restrict__ fe,
    const float* __restrict__ nodeproj,  // 1=Ujx at +98304
    float* __restrict__ xn_agg)          // pre-zeroed
{
    int b = blockIdx.x;
    int i = blockIdx.y;
    int tid = threadIdx.x;
    const float* Ujx = nodeproj + 98304;
    #pragma unroll
    for (int half = 0; half < 2; half++) {
        int c = tid + half * 256;
        float sg[12];
        float m = -1e30f;
        #pragma unroll
        for (int j = 0; j < 12; j++) {
            float e = fe[(b * 144 + i * 12 + j) * 512 + c];
            float sv = 1.f / (1.f + __expf(-e));
            sg[j] = sv;
            m = fmaxf(m, sv);
        }
        float ssum = 0.f;
        #pragma unroll
        for (int j = 0; j < 12; j++) { float evv = __expf(sg[j] - m); sg[j] = evv; ssum += evv; }
        float wgt = Ujx[(b * 12 + i) * 512 + c] / ssum;
        #pragma unroll
        for (int j = 0; j < 12; j++)
            atomicAdd(&xn_agg[(b * 12 + j) * 512 + c], sg[j] * wgt);
    }
}

// ============ GNN node update: fv = relu(fv + bn_class(Ux + agg/12)), + bf16 copy ============
__global__ __launch_bounds__(256) void gnn_node_kernel(
    const float* __restrict__ xn_agg, const float* __restrict__ nodeproj,
    float* __restrict__ fv, short* __restrict__ fv_bf)
{
    int k = blockIdx.x;
    int tid = threadIdx.x;
    const float* Ux = nodeproj;
    __shared__ float red[256];
    float vals[32];
    float sum = 0.f, sq = 0.f;
    int idx = 0;
    for (int b = 0; b < 16; b++) {
        #pragma unroll
        for (int half = 0; half < 2; half++) {
            int c = tid + half * 256;
            int o = (b * 12 + k) * 512 + c;
            float v = Ux[o] + xn_agg[o] * (1.f / 12.f);
            vals[idx++] = v;
            sum += v; sq += v * v;
        }
    }
    red[tid] = sum; __syncthreads();
    for (int t = 128; t > 0; t >>= 1) { if (tid < t) red[tid] += red[tid + t]; __syncthreads(); }
    float tsum = red[0]; __syncthreads();
    red[tid] = sq; __syncthreads();
    for (int t = 128; t > 0; t >>= 1) { if (tid < t) red[tid] += red[tid + t]; __syncthreads(); }
    float tsq = red[0];
    float mu = tsum * (1.f / 8192.f);
    float var = tsq * (1.f / 8192.f) - mu * mu;
    float rs = rsqrtf(var + BN_EPS);
    idx = 0;
    for (int b = 0; b < 16; b++) {
        #pragma unroll
        for (int half = 0; half < 2; half++) {
            int c = tid + half * 256;
            int o = (b * 12 + k) * 512 + c;
            float v = (vals[idx++] - mu) * rs;
            float nv = fmaxf(fv[o] + v, 0.f);
            fv[o] = nv;
            fv_bf[o] = f2bf(nv);
        }
    }
}

// ============ pairwise gather -> bf16 ============
__global__ __launch_bounds__(256) void pair_gather_kernel(
    const float* __restrict__ fe, const float* __restrict__ fv, short* __restrict__ pairX)
{
    int p = blockIdx.x;
    int b = blockIdx.y;
    int tid = threadIdx.x;
    int i = 0, rem = p;
    while (rem >= 11 - i) { rem -= 11 - i; i++; }
    int j = i + 1 + rem;
    short* e_out = pairX + (size_t)(b * 66 + p) * 1024;
    short* n_out = pairX + (size_t)1056 * 1024 + (size_t)(b * 66 + p) * 1024;
    const float* fe_ij = fe + (b * 144 + i * 12 + j) * 512;
    const float* fe_ji = fe + (b * 144 + j * 12 + i) * 512;
    const float* fv_i = fv + (b * 12 + i) * 512;
    const float* fv_j = fv + (b * 12 + j) * 512;
    #pragma unroll
    for (int half = 0; half < 2; half++) {
        int c = tid + half * 256;
        e_out[c] = f2bf(fe_ij[c]);
        e_out[512 + c] = f2bf(fe_ji[c]);
        n_out[c] = f2bf(fv_i[c]);
        n_out[512 + c] = f2bf(fv_j[c]);
    }
}

// ============ MLP layer 3 (Cout=4) ============
__global__ __launch_bounds__(256) void mlp3_kernel(
    const float* __restrict__ X,
    const float* __restrict__ w3,
    const float* __restrict__ b3,
    float* __restrict__ Y)
{
    int idx = blockIdx.x * 256 + threadIdx.x;
    if (idx >= 8448) return;
    int o = idx & 3;
    int r = (idx >> 2) % 1056;
    int m = idx / (4 * 1056);
    const float* x = X + (m * 1056 + r) * 256;
    const float* w = w3 + (m * 4 + o) * 256;
    float s = b3[m * 4 + o];
    #pragma unroll 8
    for (int c = 0; c < 256; c++) s += x[c] * w[c];
    Y[idx] = s;
}

// ============ final head ============
__global__ __launch_bounds__(256) void final_kernel(
    const float* __restrict__ mid3,
    const float* __restrict__ fw,
    const float* __restrict__ fb,
    float* __restrict__ out)
{
    int idx = blockIdx.x * 256 + threadIdx.x;
    if (idx >= 4224) return;
    int o = idx & 3;
    int r = idx >> 2;
    const float* ed = mid3 + r * 4;
    const float* nd = mid3 + 1056 * 4 + r * 4;
    float s = fb[o];
    #pragma unroll
    for (int q = 0; q < 4; q++) s += ed[q] * fw[o * 8 + q];
    #pragma unroll
    for (int q = 0; q < 4; q++) s += nd[q] * fw[o * 8 + 4 + q];
    out[idx] = s;
}

extern "C" void kernel_launch(void* const* d_in, const int* in_sizes, int n_in,
                              void* d_out, int out_size, void* d_ws, size_t ws_size,
                              hipStream_t stream)
{
    const float* x      = (const float*)d_in[0];
    const float* cls_w  = (const float*)d_in[1];
    const float* cls_b  = (const float*)d_in[2];
    const float* qw     = (const float*)d_in[3];
    const float* qb     = (const float*)d_in[4];
    const float* kw     = (const float*)d_in[5];
    const float* kb     = (const float*)d_in[6];
    const float* vw     = (const float*)d_in[7];
    const float* vb     = (const float*)d_in[8];
    const float* ep_w   = (const float*)d_in[9];
    const float* ep_b   = (const float*)d_in[10];
    const float* gnn_w  = (const float*)d_in[11];
    const float* mlp_w1 = (const float*)d_in[12];
    const float* mlp_b1 = (const float*)d_in[13];
    const float* mlp_w2 = (const float*)d_in[14];
    const float* mlp_b2 = (const float*)d_in[15];
    const float* mlp_w3 = (const float*)d_in[16];
    const float* mlp_b3 = (const float*)d_in[17];
    const float* fin_w  = (const float*)d_in[18];
    const float* fin_b  = (const float*)d_in[19];
    float* out = (float*)d_out;
    float* ws = (float*)d_ws;

    // ---- workspace layout (float units), ~79 MiB ----
    float* A      = ws;                  // 4816896 : h fp32 ; later q2bf+k2bf (bf16)
    float* q1b    = A + 4816896;         // 2408448 : q1bf (bf16)
    float* k1b    = q1b + 2408448;       // 200704  : k1bf (bf16)
    float* v1b    = k1b + 200704;        // 401408  : v1T (bf16)
    float* Bb     = v1b + 401408;        // 3145728 : feat_bf then w2vT (bf16)
    float* Cb     = Bb + 3145728;        // 2408448 : fu_bf -> v2bf -> GNN temps -> pair temps
    float* fv     = Cb + 2408448;        // 98304
    float* fvbf_f = fv + 98304;          // 49152
    float* bn1m   = fvbf_f + 49152;      // 6144
    float* bn1r   = bn1m + 6144;         // 6144
    float* fe     = bn1r + 6144;         // 1179648
    float* febf_f = fe + 1179648;        // 589824
    float* stats  = febf_f + 589824;     // 288
    float* xbf_f  = stats + 288;         // 200704
    float* cwbf_f = xbf_f + 200704;      // 1572864
    float* qwbf_f = cwbf_f + 1572864;    // 131072
    float* kwbf_f = qwbf_f + 131072;     // 131072
    float* vwbf_f = kwbf_f + 131072;     // 262144
    float* ewbf_f = vwbf_f + 262144;     // 131072
    float* gwbf_f = ewbf_f + 131072;     // 1310720
    float* m1bf_f = gwbf_f + 1310720;    // 524288
    float* m2bf_f = m1bf_f + 524288;     // 131072

    short* xbf   = (short*)xbf_f;
    short* cwbf  = (short*)cwbf_f;
    short* qwbf  = (short*)qwbf_f;
    short* kwbf  = (short*)kwbf_f;
    short* vwbf  = (short*)vwbf_f;
    short* ewbf  = (short*)ewbf_f;
    short* gwbf  = (short*)gwbf_f;
    short* m1wbf = (short*)m1bf_f;
    short* m2wbf = (short*)m2bf_f;

    short* fubf   = (short*)Cb;
    short* featbf = (short*)Bb;
    short* q2bf   = (short*)A;
    short* k2bf   = (short*)A + 2408448;
    short* v2bf   = (short*)Cb;
    short* w2vT   = (short*)Bb;
    short* fvbf   = (short*)fvbf_f;
    short* febf   = (short*)febf_f;
    short* q1bfb  = (short*)q1b;         // (12,16,49,256) bf16
    short* k1bfb  = (short*)k1b;         // (16,49,256) bf16
    short* v1T    = (short*)v1b;         // (16,512,64) bf16, pads zeroed

    // GNN temps in Cb (v2bf dead after w2vT-lin)
    float* nodeproj = Cb;                // 393216
    float* eE       = Cb + 393216;       // 1179648
    float* xn       = Cb + 1572864;      // 98304
    // pair temps in Cb (GNN temps dead)
    short* pairXbf  = (short*)Cb;                    // 2162688 shorts
    short* mid1bf   = (short*)Cb + 2162688;          // 1081344 shorts
    float* mid2     = Cb + 1622016;                  // 540672 floats
    float* mid3     = Cb + 2162688;                  // 8448 floats

    // 0. fused one-time conversions: x + all GEMM weights
    cvt_multi_kernel<<<4293, 256, 0, stream>>>(
        x, cls_w, qw, kw, vw, ep_w, gnn_w, mlp_w1, mlp_w2,
        xbf, cwbf, qwbf, kwbf, vwbf, ewbf, gwbf, m1wbf, m2wbf);

    // 1. h = x @ cls_w^T + cls_b  (per class)
    mfma_linear_kernel<0><<<dim3(8, 13, 12), 256, 0, stream>>>(xbf, 0, cwbf, 262144, cls_b, 512,
                                                               A, 401408, 784, 512, 512, 0);
    // 2-3. BN1 stats + fused f_u(bf16)/f_v
    hipMemsetAsync(bn1m, 0, 2 * 6144 * sizeof(float), stream);
    bn1_partial_kernel<<<dim3(12, 8), 256, 0, stream>>>(A, bn1m, bn1r);
    fu_fv_kernel<<<dim3(16, 12), 256, 0, stream>>>(A, bn1m, bn1r, fubf, fv, fvbf);
    // 4. q1 = f_u @ qw0^T + qb0 (bf16 out)
    mfma_linear_kernel<1><<<dim3(4, 147, 1), 256, 0, stream>>>(fubf, 0, qwbf, 0, qb, 0,
                                                               q1bfb, 0, 9408, 512, 256, 0);
    // 5-6. k1 (bf16), v1T (transposed bf16, pads pre-zeroed) from x
    mfma_linear_kernel<1><<<dim3(4, 13, 1), 256, 0, stream>>>(xbf, 0, kwbf, 0, kb, 0,
                                                              k1bfb, 0, 784, 512, 256, 0);
    hipMemsetAsync(v1T, 0, (size_t)16 * 512 * 64 * sizeof(short), stream);
    mfma_linear_kernel<2><<<dim3(8, 13, 1), 256, 0, stream>>>(xbf, 0, vwbf, 0, vb, 0,
                                                              v1T, 0, 784, 512, 512, 0);
    // 7. feat = attn1 (MFMA, bf16 out)
    attn1_mfma_kernel<<<dim3(16, 12), 256, 0, stream>>>(q1bfb, k1bfb, v1T, featbf);
    // 8-10. q2/k2/v2 (bf16) from feat
    mfma_linear_kernel<1><<<dim3(4, 147, 1), 256, 0, stream>>>(featbf, 0, qwbf + 131072, 0, qb + 256, 0,
                                                               q2bf, 0, 9408, 512, 256, 0);
    mfma_linear_kernel<1><<<dim3(4, 147, 1), 256, 0, stream>>>(featbf, 0, kwbf + 131072, 0, kb + 256, 0,
                                                               k2bf, 0, 9408, 512, 256, 0);
    mfma_linear_kernel<1><<<dim3(8, 147, 1), 256, 0, stream>>>(featbf, 0, vwbf + 262144, 0, vb + 512, 0,
                                                               v2bf, 0, 9408, 512, 512, 0);
    // 11. w2vT = (v2 @ ep_w^T) transposed per-tile (overlays feat; pre-zero pads)
    hipMemsetAsync(w2vT, 0, (size_t)12 * 16 * 512 * 64 * sizeof(short), stream);
    mfma_linear_kernel<2><<<dim3(8, 147, 1), 256, 0, stream>>>(v2bf, 0, ewbf, 0, nullptr, 0,
                                                               w2vT, 0, 9408, 512, 512, 0);
    // 12-14. MFMA attn2 (v4b: 512 threads, launch_bounds(512,2)) + edge BN
    hipMemsetAsync(stats, 0, 288 * sizeof(float), stream);
    attn2_mfma_kernel<<<dim3(16, 12), 512, 0, stream>>>(q2bf, k2bf, w2vT, ep_b, fe, stats);
    edge_fin_kernel<<<144, 256, 0, stream>>>(stats, fe, febf);

    // 15-16. two GCN blocks
    for (int blk = 0; blk < 2; blk++) {
        const short* gw = gwbf + blk * 5 * 262144;  // U,V,A,B,E (bf16)
        mfma_linear_kernel<0><<<dim3(8, 3, 4), 256, 0, stream>>>(fvbf, 0, gw, 262144, nullptr, 0,
                                                                 nodeproj, 98304, 192, 512, 512, 0);
        mfma_linear_kernel<0><<<dim3(8, 36, 1), 256, 0, stream>>>(febf, 0, gw + 4 * 262144, 0, nullptr, 0,
                                                                  eE, 0, 2304, 512, 512, 0);
        gnn_edge_kernel<<<144, 256, 0, stream>>>(nodeproj, eE, fe, febf);
        hipMemsetAsync(xn, 0, 98304 * sizeof(float), stream);
        gnn_agg_kernel<<<dim3(16, 12), 256, 0, stream>>>(fe, nodeproj, xn);
        gnn_node_kernel<<<12, 256, 0, stream>>>(xn, nodeproj, fv, fvbf);
    }

    // 17. pairwise gather (bf16 out)
    pair_gather_kernel<<<dim3(66, 16), 256, 0, stream>>>(fe, fv, pairXbf);
    // 18-19. MLP layers 1-2
    mfma_linear_kernel<1><<<dim3(8, 17, 2), 256, 0, stream>>>(pairXbf, 1081344, m1wbf, 524288, mlp_b1, 512,
                                                              mid1bf, 540672, 1056, 1024, 512, 1);
    mfma_linear_kernel<0><<<dim3(4, 17, 2), 256, 0, stream>>>(mid1bf, 540672, m2wbf, 131072, mlp_b2, 256,
                                                              mid2, 270336, 1056, 512, 256, 1);
    // 20. MLP layer 3
    mlp3_kernel<<<33, 256, 0, stream>>>(mid2, mlp_w3, mlp_b3, mid3);
    // 21. final head
    final_kernel<<<17, 256, 0, stream>>>(mid3, fin_w, fin_b, out);
}

// Round 19
// 432.365 us; speedup vs baseline: 1.0476x; 1.0476x over previous
//
#include <hip/hip_runtime.h>

#define BN_EPS 1e-5f

typedef float f32x4 __attribute__((ext_vector_type(4)));
typedef short s16x8 __attribute__((ext_vector_type(8)));

__device__ __forceinline__ short f2bf(float f) {
    unsigned u = __builtin_bit_cast(unsigned, f);
    u = (u + 0x7fffu + ((u >> 16) & 1u)) >> 16;   // RNE
    return (short)u;
}

// ============ fused fp32 -> bf16 convert of all 9 tensors (8 elems/thread) ============
__global__ __launch_bounds__(256) void cvt_multi_kernel(
    const float* __restrict__ s0, const float* __restrict__ s1, const float* __restrict__ s2,
    const float* __restrict__ s3, const float* __restrict__ s4, const float* __restrict__ s5,
    const float* __restrict__ s6, const float* __restrict__ s7, const float* __restrict__ s8,
    short* __restrict__ d0, short* __restrict__ d1, short* __restrict__ d2,
    short* __restrict__ d3, short* __restrict__ d4, short* __restrict__ d5,
    short* __restrict__ d6, short* __restrict__ d7, short* __restrict__ d8)
{
    int idx = blockIdx.x * 256 + threadIdx.x;   // chunk of 8 floats
    const float* src; short* dst; int local;
    if      (idx <   50176) { src = s0; dst = d0; local = idx; }
    else if (idx <  443392) { src = s1; dst = d1; local = idx -   50176; }
    else if (idx <  476160) { src = s2; dst = d2; local = idx -  443392; }
    else if (idx <  508928) { src = s3; dst = d3; local = idx -  476160; }
    else if (idx <  574464) { src = s4; dst = d4; local = idx -  508928; }
    else if (idx <  607232) { src = s5; dst = d5; local = idx -  574464; }
    else if (idx <  934912) { src = s6; dst = d6; local = idx -  607232; }
    else if (idx < 1065984) { src = s7; dst = d7; local = idx -  934912; }
    else if (idx < 1098752) { src = s8; dst = d8; local = idx - 1065984; }
    else return;
    const float4* s4p = reinterpret_cast<const float4*>(src) + (size_t)local * 2;
    float4 a = s4p[0], b = s4p[1];
    s16x8 v;
    v[0] = f2bf(a.x); v[1] = f2bf(a.y); v[2] = f2bf(a.z); v[3] = f2bf(a.w);
    v[4] = f2bf(b.x); v[5] = f2bf(b.y); v[6] = f2bf(b.z); v[7] = f2bf(b.w);
    reinterpret_cast<s16x8*>(dst)[local] = v;
}

// ============ MFMA bf16 linear: Y = act(X @ W^T + b), bf16 in ============
// 64x64 tile, BK=32, 4 waves each computing a 32x32 quadrant (2x2 of 16x16x32 MFMA).
// OMODE 0: fp32 out. 1: bf16 out. 2: bf16 out transposed per-49-row tile
// -> [tile][Cout=512][64] (keys padded to 64; pad pre-zeroed by host memset).
template<int OMODE>
__global__ __launch_bounds__(256) void mfma_linear_kernel(
    const short* __restrict__ X, int Xstride,
    const short* __restrict__ W, int Wstride,
    const float* __restrict__ bias, int bstride,
    void* __restrict__ Yv, int Ystride,
    int R, int Cin, int Cout, int relu)
{
    const int mat = blockIdx.z;
    X += (size_t)mat * Xstride;
    W += (size_t)mat * Wstride;
    const float* bp = bias ? bias + mat * bstride : nullptr;
    float* Yf = (float*)Yv + (size_t)mat * Ystride;
    short* Ys = (short*)Yv + (size_t)mat * Ystride;

    const int r0 = blockIdx.y * 64;
    const int o0 = blockIdx.x * 64;

    __shared__ short As[64 * 40];
    __shared__ short Bs[64 * 40];

    const int tid = threadIdx.x;
    const int lane = tid & 63;
    const int wave = tid >> 6;
    const int wr = wave >> 1, wc = wave & 1;
    const int l15 = lane & 15;
    const int lk = lane >> 4;

    const int trow = tid >> 2;
    const int tseg = (tid & 3) * 8;

    f32x4 acc[2][2] = {};

    const int arow = r0 + trow;
    const bool aok = arow < R;
    const short* xrow = X + (size_t)arow * Cin + tseg;
    const short* wrow = W + (size_t)(o0 + trow) * Cin + tseg;

    for (int k0 = 0; k0 < Cin; k0 += 32) {
        s16x8 av = {};
        if (aok) av = *reinterpret_cast<const s16x8*>(xrow + k0);
        s16x8 bv = *reinterpret_cast<const s16x8*>(wrow + k0);
        *reinterpret_cast<s16x8*>(&As[trow * 40 + tseg]) = av;
        *reinterpret_cast<s16x8*>(&Bs[trow * 40 + tseg]) = bv;
        __syncthreads();

        s16x8 af[2], bf[2];
        #pragma unroll
        for (int mi = 0; mi < 2; mi++)
            af[mi] = *reinterpret_cast<const s16x8*>(&As[(wr * 32 + mi * 16 + l15) * 40 + lk * 8]);
        #pragma unroll
        for (int ni = 0; ni < 2; ni++)
            bf[ni] = *reinterpret_cast<const s16x8*>(&Bs[(wc * 32 + ni * 16 + l15) * 40 + lk * 8]);
        #pragma unroll
        for (int mi = 0; mi < 2; mi++)
            #pragma unroll
            for (int ni = 0; ni < 2; ni++)
                acc[mi][ni] = __builtin_amdgcn_mfma_f32_16x16x32_bf16(af[mi], bf[ni], acc[mi][ni], 0, 0, 0);
        __syncthreads();
    }

    #pragma unroll
    for (int mi = 0; mi < 2; mi++) {
        #pragma unroll
        for (int ni = 0; ni < 2; ni++) {
            int col = o0 + wc * 32 + ni * 16 + l15;
            int row0 = r0 + wr * 32 + mi * 16 + lk * 4;
            float bb = bp ? bp[col] : 0.f;
            #pragma unroll
            for (int r = 0; r < 4; r++) {
                int row = row0 + r;
                if (row < R) {
                    float v = acc[mi][ni][r] + bb;
                    if (relu) v = fmaxf(v, 0.f);
                    if (OMODE == 0) {
                        Yf[(size_t)row * Cout + col] = v;
                    } else if (OMODE == 1) {
                        Ys[(size_t)row * Cout + col] = f2bf(v);
                    } else {
                        int t = row / 49, n = row - t * 49;
                        Ys[((size_t)t * 512 + col) * 64 + n] = f2bf(v);
                    }
                }
            }
        }
    }
}

// ============ BN1 partial stats: grid (12, 8); atomicAdd (sum, sumsq) per (k,o) ============
__global__ __launch_bounds__(256) void bn1_partial_kernel(
    const float* __restrict__ h, float* __restrict__ bsum, float* __restrict__ bsq)
{
    int k = blockIdx.x;
    int part = blockIdx.y;
    int tid = threadIdx.x;
    #pragma unroll
    for (int half = 0; half < 2; half++) {
        int o = tid + half * 256;
        const float* base = h + (size_t)k * 401408 + (size_t)part * 98 * 512 + o;
        float s = 0.f, sq = 0.f;
        #pragma unroll 7
        for (int bn = 0; bn < 98; bn++) {
            float v = base[bn * 512];
            s += v; sq += v * v;
        }
        atomicAdd(&bsum[k * 512 + o], s);
        atomicAdd(&bsq[k * 512 + o], sq);
    }
}

// ============ f_u = relu(bn(h)) -> bf16; f_v = mean_n (fp32 + bf16) ============
__global__ __launch_bounds__(256) void fu_fv_kernel(
    const float* __restrict__ h, const float* __restrict__ bsum,
    const float* __restrict__ bsq, short* __restrict__ fu_bf,
    float* __restrict__ f_v, short* __restrict__ fv_bf)
{
    int b = blockIdx.x;
    int k = blockIdx.y;
    int tid = threadIdx.x;
    #pragma unroll
    for (int half = 0; half < 2; half++) {
        int o = tid + half * 256;
        float mu = bsum[k * 512 + o] * (1.f / 784.f);
        float var = bsq[k * 512 + o] * (1.f / 784.f) - mu * mu;
        float rs = rsqrtf(var + BN_EPS);
        const float* base = h + (size_t)(k * 16 + b) * 49 * 512 + o;
        short* obase = fu_bf + (size_t)(k * 16 + b) * 49 * 512 + o;
        float acc = 0.f;
        #pragma unroll 7
        for (int n = 0; n < 49; n++) {
            float v = (base[n * 512] - mu) * rs;
            v = fmaxf(v, 0.f);
            obase[n * 512] = f2bf(v);
            acc += v;
        }
        float fvv = acc * (1.f / 49.f);
        f_v[(b * 12 + k) * 512 + o] = fvv;
        fv_bf[(b * 12 + k) * 512 + o] = f2bf(fvv);
    }
}

// ============ attn1 MFMA: block per (b,k); bf16 q1/k1, v1T transposed; writes feat bf16 ============
__global__ __launch_bounds__(256) void attn1_mfma_kernel(
    const short* __restrict__ q1,   // (12,16,49,256) bf16
    const short* __restrict__ k1,   // (16,49,256) bf16
    const short* __restrict__ v1T,  // (16,512,64) bf16, pad keys zeroed
    short* __restrict__ feat)       // (12,16,49,512) bf16
{
    const int b = blockIdx.x, k = blockIdx.y;
    __shared__ float S[64 * 68];
    __shared__ short P[64 * 88];
    const int tid = threadIdx.x;
    const int lane = tid & 63, w = tid >> 6;
    const int l15 = lane & 15, lk = lane >> 4;

    for (int idx = tid; idx < 64 * 88; idx += 256) P[idx] = 0;
    const short* qb = q1 + (size_t)((k * 16 + b) * 49) * 256;
    const short* kb = k1 + (size_t)(b * 49) * 256;
    __syncthreads();

    {
        int qrow = w * 16 + l15; if (qrow > 48) qrow = 48;
        f32x4 sacc[4] = {};
        #pragma unroll
        for (int ks = 0; ks < 8; ks++) {
            s16x8 aq = *reinterpret_cast<const s16x8*>(qb + (size_t)qrow * 256 + ks * 32 + lk * 8);
            #pragma unroll
            for (int ni = 0; ni < 4; ni++) {
                int krow = ni * 16 + l15; if (krow > 48) krow = 48;
                s16x8 bk = *reinterpret_cast<const s16x8*>(kb + (size_t)krow * 256 + ks * 32 + lk * 8);
                sacc[ni] = __builtin_amdgcn_mfma_f32_16x16x32_bf16(aq, bk, sacc[ni], 0, 0, 0);
            }
        }
        #pragma unroll
        for (int ni = 0; ni < 4; ni++)
            #pragma unroll
            for (int r = 0; r < 4; r++)
                S[(w * 16 + lk * 4 + r) * 68 + ni * 16 + l15] = sacc[ni][r] * 0.0625f;
    }
    __syncthreads();

    if (tid < 196) {
        int qi = tid >> 2, sub = tid & 3;
        float ev[13];
        float m = -1e30f;
        #pragma unroll 13
        for (int t = 0; t < 13; t++) {
            int kk = sub + t * 4;
            ev[t] = (kk < 49) ? S[qi * 68 + kk] : -1e30f;
            m = fmaxf(m, ev[t]);
        }
        m = fmaxf(m, __shfl_xor(m, 1));
        m = fmaxf(m, __shfl_xor(m, 2));
        float s = 0.f;
        #pragma unroll 13
        for (int t = 0; t < 13; t++) { ev[t] = __expf(ev[t] - m); s += ev[t]; }
        s += __shfl_xor(s, 1);
        s += __shfl_xor(s, 2);
        float inv = 1.f / s;
        #pragma unroll 13
        for (int t = 0; t < 13; t++) {
            int kk = sub + t * 4;
            if (kk < 49) P[qi * 88 + kk] = f2bf(ev[t] * inv);
        }
    }
    __syncthreads();

    const short* vt = v1T + (size_t)b * 512 * 64;
    short* fb = feat + (size_t)((k * 16 + b) * 49) * 512;
    #pragma unroll
    for (int half = 0; half < 2; half++) {
        const int cb = half * 256 + w * 64;
        f32x4 pac[4][4] = {};
        #pragma unroll
        for (int ks = 0; ks < 2; ks++) {
            s16x8 bv[4];
            #pragma unroll
            for (int ni = 0; ni < 4; ni++) {
                int ch = cb + ni * 16 + l15;
                bv[ni] = *reinterpret_cast<const s16x8*>(vt + (size_t)ch * 64 + ks * 32 + lk * 8);
            }
            #pragma unroll
            for (int mi = 0; mi < 4; mi++) {
                s16x8 ap = *reinterpret_cast<const s16x8*>(&P[(mi * 16 + l15) * 88 + ks * 32 + lk * 8]);
                #pragma unroll
                for (int ni = 0; ni < 4; ni++)
                    pac[mi][ni] = __builtin_amdgcn_mfma_f32_16x16x32_bf16(ap, bv[ni], pac[mi][ni], 0, 0, 0);
            }
        }
        #pragma unroll
        for (int ni = 0; ni < 4; ni++) {
            int col = cb + ni * 16 + l15;
            #pragma unroll
            for (int mi = 0; mi < 4; mi++) {
                #pragma unroll
                for (int r = 0; r < 4; r++) {
                    int row = mi * 16 + lk * 4 + r;
                    if (row < 49)
                        fb[(size_t)row * 512 + col] = f2bf(pac[mi][ni][r]);
                }
            }
        }
    }
}

// ============ attn2 MFMA v2 (known-good 69us): block per (b,i), loops 12 j; full V in LDS ============
__global__ __launch_bounds__(256) void attn2_mfma_kernel(
    const short* __restrict__ q2,
    const short* __restrict__ k2,
    const short* __restrict__ w2vT,
    const float* __restrict__ ep_b,
    float* __restrict__ fe_raw,     // (16,144,512)
    float* __restrict__ stats)      // (144,2)
{
    const int b = blockIdx.x, i = blockIdx.y;
    __shared__ short Vs[512 * 64];  // 64 KB, swizzled
    __shared__ float S[64 * 68];
    __shared__ short P[64 * 88];
    const int tid = threadIdx.x;
    const int lane = tid & 63, w = tid >> 6;
    const int l15 = lane & 15, lk = lane >> 4;

    {
        const float4* src = reinterpret_cast<const float4*>(w2vT + (size_t)((i * 16 + b) * 512) * 64);
        float4* dst = reinterpret_cast<float4*>(Vs);
        #pragma unroll
        for (int it = 0; it < 16; it++) {
            int c = tid + it * 256;
            int ch = c >> 3, c8 = c & 7;
            dst[(ch << 3) | (c8 ^ (ch & 7))] = src[c];
        }
        for (int idx = tid; idx < 64 * 88; idx += 256) P[idx] = 0;
    }
    const short* kb = k2 + (size_t)((i * 16 + b) * 49) * 256;
    __syncthreads();

    for (int j = 0; j < 12; j++) {
        const short* qb = q2 + (size_t)((j * 16 + b) * 49) * 256;
        {
            int qrow = w * 16 + l15; if (qrow > 48) qrow = 48;
            f32x4 sacc[4] = {};
            #pragma unroll
            for (int ks = 0; ks < 8; ks++) {
                s16x8 aq = *reinterpret_cast<const s16x8*>(qb + (size_t)qrow * 256 + ks * 32 + lk * 8);
                #pragma unroll
                for (int ni = 0; ni < 4; ni++) {
                    int krow = ni * 16 + l15; if (krow > 48) krow = 48;
                    s16x8 bk = *reinterpret_cast<const s16x8*>(kb + (size_t)krow * 256 + ks * 32 + lk * 8);
                    sacc[ni] = __builtin_amdgcn_mfma_f32_16x16x32_bf16(aq, bk, sacc[ni], 0, 0, 0);
                }
            }
            #pragma unroll
            for (int ni = 0; ni < 4; ni++)
                #pragma unroll
                for (int r = 0; r < 4; r++)
                    S[(w * 16 + lk * 4 + r) * 68 + ni * 16 + l15] = sacc[ni][r] * 0.0625f;
        }
        __syncthreads();

        if (tid < 196) {
            int qi = tid >> 2, sub = tid & 3;
            float ev[13];
            float m = -1e30f;
            #pragma unroll 13
            for (int t = 0; t < 13; t++) {
                int kk = sub + t * 4;
                ev[t] = (kk < 49) ? S[qi * 68 + kk] : -1e30f;
                m = fmaxf(m, ev[t]);
            }
            m = fmaxf(m, __shfl_xor(m, 1));
            m = fmaxf(m, __shfl_xor(m, 2));
            float s = 0.f;
            #pragma unroll 13
            for (int t = 0; t < 13; t++) { ev[t] = __expf(ev[t] - m); s += ev[t]; }
            s += __shfl_xor(s, 1);
            s += __shfl_xor(s, 2);
            float inv = 1.f / s;
            #pragma unroll 13
            for (int t = 0; t < 13; t++) {
                int kk = sub + t * 4;
                if (kk < 49) P[qi * 88 + kk] = f2bf(ev[t] * inv);
            }
        }
        __syncthreads();

        const int slot = i * 12 + j;
        float tot = 0.f, csq = 0.f;
        #pragma unroll
        for (int half = 0; half < 2; half++) {
            const int cb = half * 256 + w * 64;
            f32x4 pac[4][4] = {};
            #pragma unroll
            for (int ks = 0; ks < 2; ks++) {
                s16x8 bv[4];
                #pragma unroll
                for (int ni = 0; ni < 4; ni++) {
                    int ch = cb + ni * 16 + l15;
                    int boff = ((ch * 64 + ks * 32 + lk * 8) * 2) ^ ((ch & 7) << 4);
                    bv[ni] = *reinterpret_cast<const s16x8*>(reinterpret_cast<const char*>(Vs) + boff);
                }
                #pragma unroll
                for (int mi = 0; mi < 4; mi++) {
                    s16x8 ap = *reinterpret_cast<const s16x8*>(&P[(mi * 16 + l15) * 88 + ks * 32 + lk * 8]);
                    #pragma unroll
                    for (int ni = 0; ni < 4; ni++)
                        pac[mi][ni] = __builtin_amdgcn_mfma_f32_16x16x32_bf16(ap, bv[ni], pac[mi][ni], 0, 0, 0);
                }
            }
            #pragma unroll
            for (int ni = 0; ni < 4; ni++) {
                int col = cb + ni * 16 + l15;
                float bias = ep_b[col];
                float cs = 0.f;
                #pragma unroll
                for (int mi = 0; mi < 4; mi++) {
                    #pragma unroll
                    for (int r = 0; r < 4; r++) {
                        int row = mi * 16 + lk * 4 + r;
                        if (row < 49) {
                            float sv = pac[mi][ni][r] + bias;
                            cs += sv; csq += sv * sv;
                        }
                    }
                }
                tot += cs;
                cs += __shfl_xor(cs, 16);
                cs += __shfl_xor(cs, 32);
                if (lk == 0)
                    fe_raw[((size_t)b * 144 + slot) * 512 + col] = cs * (1.f / 49.f);
            }
        }
        tot += __shfl_xor(tot, 1);  tot += __shfl_xor(tot, 2);  tot += __shfl_xor(tot, 4);
        tot += __shfl_xor(tot, 8);  tot += __shfl_xor(tot, 16); tot += __shfl_xor(tot, 32);
        csq += __shfl_xor(csq, 1);  csq += __shfl_xor(csq, 2);  csq += __shfl_xor(csq, 4);
        csq += __shfl_xor(csq, 8);  csq += __shfl_xor(csq, 16); csq += __shfl_xor(csq, 32);
        if (lane == 0) {
            atomicAdd(&stats[slot * 2], tot);
            atomicAdd(&stats[slot * 2 + 1], csq);
        }
    }
}

// ============ finalize edge BN (fp32 + bf16 copy) ============
__global__ __launch_bounds__(256) void edge_fin_kernel(
    const float* __restrict__ stats, float* __restrict__ fe, short* __restrict__ fe_bf)
{
    int s = blockIdx.x;
    const float inv = 1.f / 401408.f;
    float mu = stats[s * 2] * inv;
    float var = stats[s * 2 + 1] * inv - mu * mu;
    float rs = rsqrtf(var + BN_EPS);
    int tid = threadIdx.x;
    for (int b = 0; b < 16; b++) {
        float* p = fe + (b * 144 + s) * 512;
        short* pb = fe_bf + (b * 144 + s) * 512;
        #pragma unroll
        for (int half = 0; half < 2; half++) {
            int c = tid + half * 256;
            float nv = (p[c] - mu) * rs;
            p[c] = nv;
            pb[c] = f2bf(nv);
        }
    }
}

// ============ GNN edge update (fp32 + bf16 copy) ============
__global__ __launch_bounds__(256) void gnn_edge_kernel(
    const float* __restrict__ nodeproj,
    const float* __restrict__ eE,
    float* __restrict__ fe, short* __restrict__ fe_bf)
{
    int s = blockIdx.x;
    int i = s / 12, j = s - i * 12;
    int tid = threadIdx.x;
    const float* Vix = nodeproj + 2 * 98304;
    const float* Vjx = nodeproj + 3 * 98304;
    __shared__ float red[256];
    float msg[32];
    float sum = 0.f, sq = 0.f;
    int idx = 0;
    for (int b = 0; b < 16; b++) {
        #pragma unroll
        for (int half = 0; half < 2; half++) {
            int c = tid + half * 256;
            float v = Vjx[(b * 12 + i) * 512 + c] + Vix[(b * 12 + j) * 512 + c]
                    + eE[(b * 144 + s) * 512 + c];
            msg[idx++] = v;
            sum += v; sq += v * v;
        }
    }
    red[tid] = sum; __syncthreads();
    for (int t = 128; t > 0; t >>= 1) { if (tid < t) red[tid] += red[tid + t]; __syncthreads(); }
    float tsum = red[0]; __syncthreads();
    red[tid] = sq; __syncthreads();
    for (int t = 128; t > 0; t >>= 1) { if (tid < t) red[tid] += red[tid + t]; __syncthreads(); }
    float tsq = red[0];
    float mu = tsum * (1.f / 8192.f);
    float var = tsq * (1.f / 8192.f) - mu * mu;
    float rs = rsqrtf(var + BN_EPS);
    idx = 0;
    for (int b = 0; b < 16; b++) {
        #pragma unroll
        for (int half = 0; half < 2; half++) {
            int c = tid + half * 256;
            int o = (b * 144 + s) * 512 + c;
            float v = fmaxf((msg[idx++] - mu) * rs, 0.f);
            float nv = fe[o] + v;
            fe[o] = nv;
            fe_bf[o] = f2bf(nv);
        }
    }
}

// ============ GNN aggregation: grid (16,12); atomicAdd into xn_agg ============
__global__ __launch_bounds__(256) void gnn_agg_kernel(
    const float* __restrict__ fe,
    const float* __restrict__ nodeproj,  // 1=Ujx at +98304
    float* __restrict__ xn_agg)          // pre-zeroed
{
    int b = blockIdx.x;
    int i = blockIdx.y;
    int tid = threadIdx.x;
    const float* Ujx = nodeproj + 98304;
    #pragma unroll
    for (int half = 0; half < 2; half++) {
        int c = tid + half * 256;
        float sg[12];
        float m = -1e30f;
        #pragma unroll
        for (int j = 0; j < 12; j++) {
            float e = fe[(b * 144 + i * 12 + j) * 512 + c];
            float sv = 1.f / (1.f + __expf(-e));
            sg[j] = sv;
            m = fmaxf(m, sv);
        }
        float ssum = 0.f;
        #pragma unroll
        for (int j = 0; j < 12; j++) { float evv = __expf(sg[j] - m); sg[j] = evv; ssum += evv; }
        float wgt = Ujx[(b * 12 + i) * 512 + c] / ssum;
        #pragma unroll
        for (int j = 0; j < 12; j++)
            atomicAdd(&xn_agg[(b * 12 + j) * 512 + c], sg[j] * wgt);
    }
}

// ============ GNN node update: fv = relu(fv + bn_class(Ux + agg/12)), + bf16 copy ============
__global__ __launch_bounds__(256) void gnn_node_kernel(
    const float* __restrict__ xn_agg, const float* __restrict__ nodeproj,
    float* __restrict__ fv, short* __restrict__ fv_bf)
{
    int k = blockIdx.x;
    int tid = threadIdx.x;
    const float* Ux = nodeproj;
    __shared__ float red[256];
    float vals[32];
    float sum = 0.f, sq = 0.f;
    int idx = 0;
    for (int b = 0; b < 16; b++) {
        #pragma unroll
        for (int half = 0; half < 2; half++) {
            int c = tid + half * 256;
            int o = (b * 12 + k) * 512 + c;
            float v = Ux[o] + xn_agg[o] * (1.f / 12.f);
            vals[idx++] = v;
            sum += v; sq += v * v;
        }
    }
    red[tid] = sum; __syncthreads();
    for (int t = 128; t > 0; t >>= 1) { if (tid < t) red[tid] += red[tid + t]; __syncthreads(); }
    float tsum = red[0]; __syncthreads();
    red[tid] = sq; __syncthreads();
    for (int t = 128; t > 0; t >>= 1) { if (tid < t) red[tid] += red[tid + t]; __syncthreads(); }
    float tsq = red[0];
    float mu = tsum * (1.f / 8192.f);
    float var = tsq * (1.f / 8192.f) - mu * mu;
    float rs = rsqrtf(var + BN_EPS);
    idx = 0;
    for (int b = 0; b < 16; b++) {
        #pragma unroll
        for (int half = 0; half < 2; half++) {
            int c = tid + half * 256;
            int o = (b * 12 + k) * 512 + c;
            float v = (vals[idx++] - mu) * rs;
            float nv = fmaxf(fv[o] + v, 0.f);
            fv[o] = nv;
            fv_bf[o] = f2bf(nv);
        }
    }
}

// ============ pairwise gather -> bf16 ============
__global__ __launch_bounds__(256) void pair_gather_kernel(
    const float* __restrict__ fe, const float* __restrict__ fv, short* __restrict__ pairX)
{
    int p = blockIdx.x;
    int b = blockIdx.y;
    int tid = threadIdx.x;
    int i = 0, rem = p;
    while (rem >= 11 - i) { rem -= 11 - i; i++; }
    int j = i + 1 + rem;
    short* e_out = pairX + (size_t)(b * 66 + p) * 1024;
    short* n_out = pairX + (size_t)1056 * 1024 + (size_t)(b * 66 + p) * 1024;
    const float* fe_ij = fe + (b * 144 + i * 12 + j) * 512;
    const float* fe_ji = fe + (b * 144 + j * 12 + i) * 512;
    const float* fv_i = fv + (b * 12 + i) * 512;
    const float* fv_j = fv + (b * 12 + j) * 512;
    #pragma unroll
    for (int half = 0; half < 2; half++) {
        int c = tid + half * 256;
        e_out[c] = f2bf(fe_ij[c]);
        e_out[512 + c] = f2bf(fe_ji[c]);
        n_out[c] = f2bf(fv_i[c]);
        n_out[512 + c] = f2bf(fv_j[c]);
    }
}

// ============ MLP layer 3 (Cout=4) ============
__global__ __launch_bounds__(256) void mlp3_kernel(
    const float* __restrict__ X,
    const float* __restrict__ w3,
    const float* __restrict__ b3,
    float* __restrict__ Y)
{
    int idx = blockIdx.x * 256 + threadIdx.x;
    if (idx >= 8448) return;
    int o = idx & 3;
    int r = (idx >> 2) % 1056;
    int m = idx / (4 * 1056);
    const float* x = X + (m * 1056 + r) * 256;
    const float* w = w3 + (m * 4 + o) * 256;
    float s = b3[m * 4 + o];
    #pragma unroll 8
    for (int c = 0; c < 256; c++) s += x[c] * w[c];
    Y[idx] = s;
}

// ============ final head ============
__global__ __launch_bounds__(256) void final_kernel(
    const float* __restrict__ mid3,
    const float* __restrict__ fw,
    const float* __restrict__ fb,
    float* __restrict__ out)
{
    int idx = blockIdx.x * 256 + threadIdx.x;
    if (idx >= 4224) return;
    int o = idx & 3;
    int r = idx >> 2;
    const float* ed = mid3 + r * 4;
    const float* nd = mid3 + 1056 * 4 + r * 4;
    float s = fb[o];
    #pragma unroll
    for (int q = 0; q < 4; q++) s += ed[q] * fw[o * 8 + q];
    #pragma unroll
    for (int q = 0; q < 4; q++) s += nd[q] * fw[o * 8 + 4 + q];
    out[idx] = s;
}

extern "C" void kernel_launch(void* const* d_in, const int* in_sizes, int n_in,
                              void* d_out, int out_size, void* d_ws, size_t ws_size,
                              hipStream_t stream)
{
    const float* x      = (const float*)d_in[0];
    const float* cls_w  = (const float*)d_in[1];
    const float* cls_b  = (const float*)d_in[2];
    const float* qw     = (const float*)d_in[3];
    const float* qb     = (const float*)d_in[4];
    const float* kw     = (const float*)d_in[5];
    const float* kb     = (const float*)d_in[6];
    const float* vw     = (const float*)d_in[7];
    const float* vb     = (const float*)d_in[8];
    const float* ep_w   = (const float*)d_in[9];
    const float* ep_b   = (const float*)d_in[10];
    const float* gnn_w  = (const float*)d_in[11];
    const float* mlp_w1 = (const float*)d_in[12];
    const float* mlp_b1 = (const float*)d_in[13];
    const float* mlp_w2 = (const float*)d_in[14];
    const float* mlp_b2 = (const float*)d_in[15];
    const float* mlp_w3 = (const float*)d_in[16];
    const float* mlp_b3 = (const float*)d_in[17];
    const float* fin_w  = (const float*)d_in[18];
    const float* fin_b  = (const float*)d_in[19];
    float* out = (float*)d_out;
    float* ws = (float*)d_ws;

    // ---- workspace layout (float units), ~79 MiB ----
    float* A      = ws;                  // 4816896 : h fp32 ; later q2bf+k2bf (bf16)
    float* q1b    = A + 4816896;         // 2408448 : q1bf (bf16)
    float* k1b    = q1b + 2408448;       // 200704  : k1bf (bf16)
    float* v1b    = k1b + 200704;        // 401408  : v1T (bf16)
    float* Bb     = v1b + 401408;        // 3145728 : feat_bf then w2vT (bf16)
    float* Cb     = Bb + 3145728;        // 2408448 : fu_bf -> v2bf -> GNN temps -> pair temps
    float* fv     = Cb + 2408448;        // 98304
    float* fvbf_f = fv + 98304;          // 49152
    float* bn1m   = fvbf_f + 49152;      // 6144
    float* bn1r   = bn1m + 6144;         // 6144
    float* fe     = bn1r + 6144;         // 1179648
    float* febf_f = fe + 1179648;        // 589824
    float* stats  = febf_f + 589824;     // 288
    float* xbf_f  = stats + 288;         // 200704
    float* cwbf_f = xbf_f + 200704;      // 1572864
    float* qwbf_f = cwbf_f + 1572864;    // 131072
    float* kwbf_f = qwbf_f + 131072;     // 131072
    float* vwbf_f = kwbf_f + 131072;     // 262144
    float* ewbf_f = vwbf_f + 262144;     // 131072
    float* gwbf_f = ewbf_f + 131072;     // 1310720
    float* m1bf_f = gwbf_f + 1310720;    // 524288
    float* m2bf_f = m1bf_f + 524288;     // 131072

    short* xbf   = (short*)xbf_f;
    short* cwbf  = (short*)cwbf_f;
    short* qwbf  = (short*)qwbf_f;
    short* kwbf  = (short*)kwbf_f;
    short* vwbf  = (short*)vwbf_f;
    short* ewbf  = (short*)ewbf_f;
    short* gwbf  = (short*)gwbf_f;
    short* m1wbf = (short*)m1bf_f;
    short* m2wbf = (short*)m2bf_f;

    short* fubf   = (short*)Cb;
    short* featbf = (short*)Bb;
    short* q2bf   = (short*)A;
    short* k2bf   = (short*)A + 2408448;
    short* v2bf   = (short*)Cb;
    short* w2vT   = (short*)Bb;
    short* fvbf   = (short*)fvbf_f;
    short* febf   = (short*)febf_f;
    short* q1bfb  = (short*)q1b;         // (12,16,49,256) bf16
    short* k1bfb  = (short*)k1b;         // (16,49,256) bf16
    short* v1T    = (short*)v1b;         // (16,512,64) bf16, pads zeroed

    // GNN temps in Cb (v2bf dead after w2vT-lin)
    float* nodeproj = Cb;                // 393216
    float* eE       = Cb + 393216;       // 1179648
    float* xn       = Cb + 1572864;      // 98304
    // pair temps in Cb (GNN temps dead)
    short* pairXbf  = (short*)Cb;                    // 2162688 shorts
    short* mid1bf   = (short*)Cb + 2162688;          // 1081344 shorts
    float* mid2     = Cb + 1622016;                  // 540672 floats
    float* mid3     = Cb + 2162688;                  // 8448 floats

    // 0. fused one-time conversions: x + all GEMM weights
    cvt_multi_kernel<<<4293, 256, 0, stream>>>(
        x, cls_w, qw, kw, vw, ep_w, gnn_w, mlp_w1, mlp_w2,
        xbf, cwbf, qwbf, kwbf, vwbf, ewbf, gwbf, m1wbf, m2wbf);

    // 1. h = x @ cls_w^T + cls_b  (per class)
    mfma_linear_kernel<0><<<dim3(8, 13, 12), 256, 0, stream>>>(xbf, 0, cwbf, 262144, cls_b, 512,
                                                               A, 401408, 784, 512, 512, 0);
    // 2-3. BN1 stats + fused f_u(bf16)/f_v
    hipMemsetAsync(bn1m, 0, 2 * 6144 * sizeof(float), stream);
    bn1_partial_kernel<<<dim3(12, 8), 256, 0, stream>>>(A, bn1m, bn1r);
    fu_fv_kernel<<<dim3(16, 12), 256, 0, stream>>>(A, bn1m, bn1r, fubf, fv, fvbf);
    // 4. q1 = f_u @ qw0^T + qb0 (bf16 out)
    mfma_linear_kernel<1><<<dim3(4, 147, 1), 256, 0, stream>>>(fubf, 0, qwbf, 0, qb, 0,
                                                               q1bfb, 0, 9408, 512, 256, 0);
    // 5-6. k1 (bf16), v1T (transposed bf16, pads pre-zeroed) from x
    mfma_linear_kernel<1><<<dim3(4, 13, 1), 256, 0, stream>>>(xbf, 0, kwbf, 0, kb, 0,
                                                              k1bfb, 0, 784, 512, 256, 0);
    hipMemsetAsync(v1T, 0, (size_t)16 * 512 * 64 * sizeof(short), stream);
    mfma_linear_kernel<2><<<dim3(8, 13, 1), 256, 0, stream>>>(xbf, 0, vwbf, 0, vb, 0,
                                                              v1T, 0, 784, 512, 512, 0);
    // 7. feat = attn1 (MFMA, bf16 out)
    attn1_mfma_kernel<<<dim3(16, 12), 256, 0, stream>>>(q1bfb, k1bfb, v1T, featbf);
    // 8-10. q2/k2/v2 (bf16) from feat
    mfma_linear_kernel<1><<<dim3(4, 147, 1), 256, 0, stream>>>(featbf, 0, qwbf + 131072, 0, qb + 256, 0,
                                                               q2bf, 0, 9408, 512, 256, 0);
    mfma_linear_kernel<1><<<dim3(4, 147, 1), 256, 0, stream>>>(featbf, 0, kwbf + 131072, 0, kb + 256, 0,
                                                               k2bf, 0, 9408, 512, 256, 0);
    mfma_linear_kernel<1><<<dim3(8, 147, 1), 256, 0, stream>>>(featbf, 0, vwbf + 262144, 0, vb + 512, 0,
                                                               v2bf, 0, 9408, 512, 512, 0);
    // 11. w2vT = (v2 @ ep_w^T) transposed per-tile (overlays feat; pre-zero pads)
    hipMemsetAsync(w2vT, 0, (size_t)12 * 16 * 512 * 64 * sizeof(short), stream);
    mfma_linear_kernel<2><<<dim3(8, 147, 1), 256, 0, stream>>>(v2bf, 0, ewbf, 0, nullptr, 0,
                                                               w2vT, 0, 9408, 512, 512, 0);
    // 12-14. MFMA attn2 (v2: V-in-LDS, 12 j per block) + edge BN
    hipMemsetAsync(stats, 0, 288 * sizeof(float), stream);
    attn2_mfma_kernel<<<dim3(16, 12), 256, 0, stream>>>(q2bf, k2bf, w2vT, ep_b, fe, stats);
    edge_fin_kernel<<<144, 256, 0, stream>>>(stats, fe, febf);

    // 15-16. two GCN blocks
    for (int blk = 0; blk < 2; blk++) {
        const short* gw = gwbf + blk * 5 * 262144;  // U,V,A,B,E (bf16)
        mfma_linear_kernel<0><<<dim3(8, 3, 4), 256, 0, stream>>>(fvbf, 0, gw, 262144, nullptr, 0,
                                                                 nodeproj, 98304, 192, 512, 512, 0);
        mfma_linear_kernel<0><<<dim3(8, 36, 1), 256, 0, stream>>>(febf, 0, gw + 4 * 262144, 0, nullptr, 0,
                                                                  eE, 0, 2304, 512, 512, 0);
        gnn_edge_kernel<<<144, 256, 0, stream>>>(nodeproj, eE, fe, febf);
        hipMemsetAsync(xn, 0, 98304 * sizeof(float), stream);
        gnn_agg_kernel<<<dim3(16, 12), 256, 0, stream>>>(fe, nodeproj, xn);
        gnn_node_kernel<<<12, 256, 0, stream>>>(xn, nodeproj, fv, fvbf);
    }

    // 17. pairwise gather (bf16 out)
    pair_gather_kernel<<<dim3(66, 16), 256, 0, stream>>>(fe, fv, pairXbf);
    // 18-19. MLP layers 1-2
    mfma_linear_kernel<1><<<dim3(8, 17, 2), 256, 0, stream>>>(pairXbf, 1081344, m1wbf, 524288, mlp_b1, 512,
                                                              mid1bf, 540672, 1056, 1024, 512, 1);
    mfma_linear_kernel<0><<<dim3(4, 17, 2), 256, 0, stream>>>(mid1bf, 540672, m2wbf, 131072, mlp_b2, 256,
                                                              mid2, 270336, 1056, 512, 256, 1);
    // 20. MLP layer 3
    mlp3_kernel<<<33, 256, 0, stream>>>(mid2, mlp_w3, mlp_b3, mid3);
    // 21. final head
    final_kernel<<<17, 256, 0, stream>>>(mid3, fin_w, fin_b, out);
}